// Round 1
// baseline (718.551 us; speedup 1.0000x reference)
//
#include <hip/hip_runtime.h>

// SparseGCN: 3-layer GCN, N=50000 nodes, E=800000 edges, dims 128->64->64->64.
// Reference (PyG gcn_norm, add_self_loops=True):
//   deg[i] = 1 + #incoming edges at i; dinv = rsqrt(deg)
//   per layer: h = x@W; out[dst] += dinv[src]*dinv[dst]*h[src] (+ self loop dinv[i]^2*h[i]); out += b; relu (layers 1,2)

#define FD 64  // feature dim of all hidden/output layers

__global__ void init_deg(float* deg, int n) {
    int i = blockIdx.x * blockDim.x + threadIdx.x;
    if (i < n) deg[i] = 1.0f;  // self-loop
}

__global__ void accum_deg(const int* __restrict__ dst, float* deg, int E) {
    int e = blockIdx.x * blockDim.x + threadIdx.x;
    if (e < E) atomicAdd(&deg[dst[e]], 1.0f);
}

__global__ void make_dinv(float* deg, int n) {
    int i = blockIdx.x * blockDim.x + threadIdx.x;
    if (i < n) deg[i] = rsqrtf(deg[i]);  // deg >= 1 always (self-loop)
}

// Dense h = x @ W  (x: nrows x K, W: K x 64, h: nrows x 64)
// Block: 256 threads = 4 waves; each block does 16 rows; W + 16 x-rows staged in LDS.
template <int K>
__global__ void gemm_kernel(const float* __restrict__ x, const float* __restrict__ W,
                            float* __restrict__ out, int nrows) {
    __shared__ float Ws[K * FD];
    __shared__ float Xs[16 * K];
    const int tid = threadIdx.x;
    for (int i = tid; i < K * FD; i += 256) Ws[i] = W[i];
    const int rowBase = blockIdx.x * 16;
    for (int i = tid; i < 16 * K; i += 256) {
        int r = rowBase + (i >> (K == 128 ? 7 : 6));
        int k = i & (K - 1);
        Xs[i] = (r < nrows) ? x[(size_t)r * K + k] : 0.0f;
    }
    __syncthreads();
    const int lane = tid & 63;
    const int wave = tid >> 6;
    for (int rr = 0; rr < 4; ++rr) {
        int lr = wave * 4 + rr;
        int r = rowBase + lr;
        if (r < nrows) {
            float acc = 0.0f;
#pragma unroll
            for (int k = 0; k < K; ++k)
                acc = fmaf(Xs[lr * K + k], Ws[k * FD + lane], acc);
            out[(size_t)r * FD + lane] = acc;
        }
    }
}

// One wave per edge: out[dst,:] += dinv[src]*dinv[dst] * h[src,:]
__global__ void agg_kernel(const int* __restrict__ src, const int* __restrict__ dst,
                           const float* __restrict__ dinv, const float* __restrict__ h,
                           float* out, int E) {
    int w = (blockIdx.x * blockDim.x + threadIdx.x) >> 6;
    int lane = threadIdx.x & 63;
    if (w >= E) return;
    int s = src[w];
    int d = dst[w];
    float nrm = dinv[s] * dinv[d];
    float v = nrm * h[(size_t)s * FD + lane];
    atomicAdd(&out[(size_t)d * FD + lane], v);
}

// out = agg + dinv^2 * h + b, optional relu
template <bool RELU>
__global__ void fin_kernel(const float* __restrict__ agg, const float* __restrict__ h,
                           const float* __restrict__ dinv, const float* __restrict__ b,
                           float* __restrict__ out, int total) {
    int i = blockIdx.x * blockDim.x + threadIdx.x;
    if (i >= total) return;
    int node = i >> 6;
    int l = i & 63;
    float di = dinv[node];
    float v = agg[i] + di * di * h[i] + b[l];
    if (RELU) v = fmaxf(v, 0.0f);
    out[i] = v;
}

extern "C" void kernel_launch(void* const* d_in, const int* in_sizes, int n_in,
                              void* d_out, int out_size, void* d_ws, size_t ws_size,
                              hipStream_t stream) {
    const float* x  = (const float*)d_in[0];
    const int*   ei = (const int*)d_in[1];
    const float* W1 = (const float*)d_in[2];
    const float* b1 = (const float*)d_in[3];
    const float* W2 = (const float*)d_in[4];
    const float* b2 = (const float*)d_in[5];
    const float* W3 = (const float*)d_in[6];
    const float* b3 = (const float*)d_in[7];
    float* out = (float*)d_out;

    const int N = in_sizes[0] / 128;   // 50000
    const int E = in_sizes[1] / 2;     // 800000
    const int* src = ei;
    const int* dst = ei + E;

    float* bufA = (float*)d_ws;                 // N*64 floats
    float* bufB = bufA + (size_t)N * FD;        // N*64 floats
    float* dinv = bufB + (size_t)N * FD;        // N floats
    const size_t featBytes = (size_t)N * FD * sizeof(float);

    const int total = N * FD;
    dim3 blk(256);
    dim3 gN((N + 255) / 256);
    dim3 gE((E + 255) / 256);
    dim3 gGemm((N + 15) / 16);
    dim3 gAgg((E + 3) / 4);          // 1 wave per edge, 4 edges per 256-thr block
    dim3 gFin((total + 255) / 256);

    // degree -> dinv
    init_deg<<<gN, blk, 0, stream>>>(dinv, N);
    accum_deg<<<gE, blk, 0, stream>>>(dst, dinv, E);
    make_dinv<<<gN, blk, 0, stream>>>(dinv, N);

    // ---- Layer 1: x(128) -> bufA; agg -> bufB; fin(relu) -> bufA
    gemm_kernel<128><<<gGemm, blk, 0, stream>>>(x, W1, bufA, N);
    hipMemsetAsync(bufB, 0, featBytes, stream);
    agg_kernel<<<gAgg, blk, 0, stream>>>(src, dst, dinv, bufA, bufB, E);
    fin_kernel<true><<<gFin, blk, 0, stream>>>(bufB, bufA, dinv, b1, bufA, total);

    // ---- Layer 2: bufA(64) -> bufB; agg -> bufA; fin(relu) -> bufB
    gemm_kernel<64><<<gGemm, blk, 0, stream>>>(bufA, W2, bufB, N);
    hipMemsetAsync(bufA, 0, featBytes, stream);
    agg_kernel<<<gAgg, blk, 0, stream>>>(src, dst, dinv, bufB, bufA, E);
    fin_kernel<true><<<gFin, blk, 0, stream>>>(bufA, bufB, dinv, b2, bufB, total);

    // ---- Layer 3: bufB(64) -> bufA; agg -> d_out; fin(no relu) -> d_out
    gemm_kernel<64><<<gGemm, blk, 0, stream>>>(bufB, W3, bufA, N);
    hipMemsetAsync(out, 0, featBytes, stream);
    agg_kernel<<<gAgg, blk, 0, stream>>>(src, dst, dinv, bufA, out, E);
    fin_kernel<false><<<gFin, blk, 0, stream>>>(out, bufA, dinv, b3, out, total);
}

// Round 2
// 363.833 us; speedup vs baseline: 1.9749x; 1.9749x over previous
//
#include <hip/hip_runtime.h>

// SparseGCN: 3-layer GCN, N=50000, E=800000, dims 128->64->64->64.
// Strategy: build dst-CSR once per call (no fp atomics in hot path), then
// pull-aggregation: one wave per node, lane = feature, fused epilogue.
// h' = dinv[row] * (x @ W)  (GEMM epilogue), then
// out[d] = relu( dinv[d] * (sum_{s in N(d)} h'[s] + h'[d]) + b )

#define FD 64

__global__ void zero_int(int* p, int n) {
    int i = blockIdx.x * blockDim.x + threadIdx.x;
    if (i < n) p[i] = 0;
}

__global__ void count_dst(const int* __restrict__ dst, int* __restrict__ cnt, int E) {
    int e = blockIdx.x * blockDim.x + threadIdx.x;
    if (e < E) atomicAdd(&cnt[dst[e]], 1);
}

// Single-workgroup scan over N counts: rowptr = exclusive prefix, cursor = copy,
// dinv[i] = rsqrt(cnt[i]+1). Wave-shuffle scan, 2 barriers per 1024-chunk.
__global__ __launch_bounds__(1024) void scan_kernel(const int* __restrict__ cnt,
                                                    int* __restrict__ rowptr,
                                                    int* __restrict__ cursor,
                                                    float* __restrict__ dinv, int n) {
    __shared__ int wsum[16];
    __shared__ int carry;
    const int tid = threadIdx.x, lane = tid & 63, wv = tid >> 6;
    if (tid == 0) carry = 0;
    __syncthreads();
    for (int base = 0; base < n; base += 1024) {
        int i = base + tid;
        int v = (i < n) ? cnt[i] : 0;
        if (i < n) dinv[i] = rsqrtf((float)(v + 1));
        // inclusive wave scan
        int x = v;
        for (int off = 1; off < 64; off <<= 1) {
            int t = __shfl_up(x, off, 64);
            if (lane >= off) x += t;
        }
        if (lane == 63) wsum[wv] = x;
        __syncthreads();
        if (wv == 0 && lane < 16) {
            int w = wsum[lane];
            for (int off = 1; off < 16; off <<= 1) {
                int t = __shfl_up(w, off, 64);
                if (lane >= off) w += t;
            }
            wsum[lane] = w;  // inclusive scan of wave sums
        }
        __syncthreads();
        int wave_excl = (wv == 0) ? 0 : wsum[wv - 1];
        int excl = x - v + wave_excl;
        int rp = carry + excl;
        if (i < n) { rowptr[i] = rp; cursor[i] = rp; }
        __syncthreads();
        if (tid == 0) carry += wsum[15];
        __syncthreads();
    }
    if (threadIdx.x == 0) rowptr[n] = carry;
}

__global__ void build_csr(const int* __restrict__ src, const int* __restrict__ dst,
                          int* __restrict__ cursor, int* __restrict__ csr_src, int E) {
    int e = blockIdx.x * blockDim.x + threadIdx.x;
    if (e < E) {
        int pos = atomicAdd(&cursor[dst[e]], 1);
        csr_src[pos] = src[e];
    }
}

// Dense h' = dinv[row] * (x @ W)  (x: nrows x K, W: K x 64)
// 256 threads = 4 waves, 16 rows per block; W + 16 x-rows staged in LDS.
template <int K>
__global__ void gemm_kernel(const float* __restrict__ x, const float* __restrict__ W,
                            const float* __restrict__ dinv, float* __restrict__ out,
                            int nrows) {
    __shared__ float Ws[K * FD];
    __shared__ float Xs[16 * K];
    const int tid = threadIdx.x;
    for (int i = tid; i < K * FD; i += 256) Ws[i] = W[i];
    const int rowBase = blockIdx.x * 16;
    for (int i = tid; i < 16 * K; i += 256) {
        int r = rowBase + (i >> (K == 128 ? 7 : 6));
        int k = i & (K - 1);
        Xs[i] = (r < nrows) ? x[(size_t)r * K + k] : 0.0f;
    }
    __syncthreads();
    const int lane = tid & 63;
    const int wave = tid >> 6;
    for (int rr = 0; rr < 4; ++rr) {
        int lr = wave * 4 + rr;
        int r = rowBase + lr;
        if (r < nrows) {
            float acc = 0.0f;
#pragma unroll
            for (int k = 0; k < K; ++k)
                acc = fmaf(Xs[lr * K + k], Ws[k * FD + lane], acc);
            out[(size_t)r * FD + lane] = acc * dinv[r];
        }
    }
}

// Pull aggregation + fused epilogue. One wave per node, lane = feature.
template <bool RELU>
__global__ void agg_fused(const int* __restrict__ rowptr, const int* __restrict__ csr_src,
                          const float* __restrict__ dinv, const float* __restrict__ h,
                          const float* __restrict__ b, float* __restrict__ out, int N) {
    int node = (blockIdx.x * blockDim.x + threadIdx.x) >> 6;
    int lane = threadIdx.x & 63;
    if (node >= N) return;
    int beg = rowptr[node], end = rowptr[node + 1];
    float acc = h[(size_t)node * FD + lane];  // self-loop term (h already dinv-scaled)
    int j = beg;
    for (; j + 3 < end; j += 4) {
        int s0 = csr_src[j], s1 = csr_src[j + 1], s2 = csr_src[j + 2], s3 = csr_src[j + 3];
        float a0 = h[(size_t)s0 * FD + lane];
        float a1 = h[(size_t)s1 * FD + lane];
        float a2 = h[(size_t)s2 * FD + lane];
        float a3 = h[(size_t)s3 * FD + lane];
        acc += (a0 + a1) + (a2 + a3);
    }
    for (; j < end; ++j) {
        int s = csr_src[j];
        acc += h[(size_t)s * FD + lane];
    }
    float v = fmaf(dinv[node], acc, b[lane]);
    if (RELU) v = fmaxf(v, 0.0f);
    out[(size_t)node * FD + lane] = v;
}

extern "C" void kernel_launch(void* const* d_in, const int* in_sizes, int n_in,
                              void* d_out, int out_size, void* d_ws, size_t ws_size,
                              hipStream_t stream) {
    const float* x  = (const float*)d_in[0];
    const int*   ei = (const int*)d_in[1];
    const float* W1 = (const float*)d_in[2];
    const float* b1 = (const float*)d_in[3];
    const float* W2 = (const float*)d_in[4];
    const float* b2 = (const float*)d_in[5];
    const float* W3 = (const float*)d_in[6];
    const float* b3 = (const float*)d_in[7];
    float* out = (float*)d_out;

    const int N = in_sizes[0] / 128;   // 50000
    const int E = in_sizes[1] / 2;     // 800000
    const int* src = ei;
    const int* dst = ei + E;

    // workspace layout
    float* bufA   = (float*)d_ws;                   // N*FD
    float* bufB   = bufA + (size_t)N * FD;          // N*FD
    float* dinv   = bufB + (size_t)N * FD;          // N
    int*   cnt    = (int*)(dinv + N);               // N
    int*   rowptr = cnt + N;                        // N+1
    int*   cursor = rowptr + N + 1;                 // N
    int*   csr    = cursor + N;                     // E

    dim3 blk(256);
    dim3 gN((N + 255) / 256);
    dim3 gE((E + 255) / 256);
    dim3 gGemm((N + 15) / 16);
    dim3 gAgg(((size_t)N * 64 + 255) / 256);  // one wave per node

    // CSR build (per call; inputs immutable)
    zero_int<<<gN, blk, 0, stream>>>(cnt, N);
    count_dst<<<gE, blk, 0, stream>>>(dst, cnt, E);
    scan_kernel<<<1, 1024, 0, stream>>>(cnt, rowptr, cursor, dinv, N);
    build_csr<<<gE, blk, 0, stream>>>(src, dst, cursor, csr, E);

    // Layer 1: x(128) -> bufA -> agg -> bufB
    gemm_kernel<128><<<gGemm, blk, 0, stream>>>(x, W1, dinv, bufA, N);
    agg_fused<true><<<gAgg, blk, 0, stream>>>(rowptr, csr, dinv, bufA, b1, bufB, N);

    // Layer 2: bufB -> bufA -> agg -> bufB
    gemm_kernel<64><<<gGemm, blk, 0, stream>>>(bufB, W2, dinv, bufA, N);
    agg_fused<true><<<gAgg, blk, 0, stream>>>(rowptr, csr, dinv, bufA, b2, bufB, N);

    // Layer 3: bufB -> bufA -> agg -> out
    gemm_kernel<64><<<gGemm, blk, 0, stream>>>(bufB, W3, dinv, bufA, N);
    agg_fused<false><<<gAgg, blk, 0, stream>>>(rowptr, csr, dinv, bufA, b3, out, N);
}

// Round 3
// 314.351 us; speedup vs baseline: 2.2858x; 1.1574x over previous
//
#include <hip/hip_runtime.h>

// SparseGCN: 3-layer GCN, N=50000, E=800000, dims 128->64->64->64.
// dst-CSR built per call (multi-block scan, no fp atomics), pull-aggregation
// with fused epilogue. h' = dinv[row]*(x@W); out[d] = relu(dinv[d]*(sum h'[s] + h'[d]) + b).

#define FD 64
#define SCHUNK 2048  // elements per scan block (256 thr x 8)

__global__ void count_dst(const int* __restrict__ dst, int* __restrict__ cnt, int E) {
    int e = blockIdx.x * blockDim.x + threadIdx.x;
    if (e < E) atomicAdd(&cnt[dst[e]], 1);
}

// A: per-block partial sums of cnt
__global__ void scan_partial(const int* __restrict__ cnt, int* __restrict__ bsum, int n) {
    __shared__ int wsum[4];
    const int tid = threadIdx.x, lane = tid & 63, wv = tid >> 6;
    int base = blockIdx.x * SCHUNK + tid * 8;
    int s = 0;
#pragma unroll
    for (int k = 0; k < 8; ++k) {
        int i = base + k;
        if (i < n) s += cnt[i];
    }
    for (int off = 1; off < 64; off <<= 1) s += __shfl_xor(s, off, 64);
    if (lane == 0) wsum[wv] = s;
    __syncthreads();
    if (tid == 0) bsum[blockIdx.x] = wsum[0] + wsum[1] + wsum[2] + wsum[3];
}

// B: exclusive scan of block sums (single wave, loops if >64 blocks)
__global__ void scan_blocksums(int* bsum, int nblk) {
    int lane = threadIdx.x;
    int carry = 0;
    for (int base = 0; base < nblk; base += 64) {
        int i = base + lane;
        int v = (i < nblk) ? bsum[i] : 0;
        int x = v;
        for (int off = 1; off < 64; off <<= 1) {
            int t = __shfl_up(x, off, 64);
            if (lane >= off) x += t;
        }
        if (i < nblk) bsum[i] = carry + x - v;
        carry += __shfl(x, 63, 64);
    }
}

// C: final scan: rowptr/cursor = exclusive prefix, dinv = rsqrt(cnt+1)
__global__ void scan_final(const int* __restrict__ cnt, const int* __restrict__ bsum,
                           int* __restrict__ rowptr, int* __restrict__ cursor,
                           float* __restrict__ dinv, int n, int E) {
    __shared__ int wofs[4];
    const int tid = threadIdx.x, lane = tid & 63, wv = tid >> 6;
    int base = blockIdx.x * SCHUNK + tid * 8;
    int vals[8];
    int s = 0;
#pragma unroll
    for (int k = 0; k < 8; ++k) {
        int i = base + k;
        vals[k] = (i < n) ? cnt[i] : 0;
        s += vals[k];
    }
    int x = s;
    for (int off = 1; off < 64; off <<= 1) {
        int t = __shfl_up(x, off, 64);
        if (lane >= off) x += t;
    }
    if (lane == 63) wofs[wv] = x;
    __syncthreads();
    int wex = 0;
    for (int i = 0; i < wv; ++i) wex += wofs[i];
    int run = (x - s) + wex + bsum[blockIdx.x];
#pragma unroll
    for (int k = 0; k < 8; ++k) {
        int i = base + k;
        if (i < n) {
            rowptr[i] = run;
            cursor[i] = run;
            dinv[i] = rsqrtf((float)(vals[k] + 1));
            run += vals[k];
        }
    }
    if (blockIdx.x == 0 && tid == 0) rowptr[n] = E;
}

__global__ void build_csr(const int* __restrict__ src, const int* __restrict__ dst,
                          int* __restrict__ cursor, int* __restrict__ csr_src, int E) {
    int e = blockIdx.x * blockDim.x + threadIdx.x;
    if (e < E) {
        int pos = atomicAdd(&cursor[dst[e]], 1);
        csr_src[pos] = src[e];
    }
}

// Dense h' = dinv[row] * (x @ W)  (x: nrows x K, W: K x 64)
template <int K>
__global__ void gemm_kernel(const float* __restrict__ x, const float* __restrict__ W,
                            const float* __restrict__ dinv, float* __restrict__ out,
                            int nrows) {
    __shared__ float Ws[K * FD];
    __shared__ float Xs[16 * K];
    const int tid = threadIdx.x;
    for (int i = tid; i < K * FD; i += 256) Ws[i] = W[i];
    const int rowBase = blockIdx.x * 16;
    for (int i = tid; i < 16 * K; i += 256) {
        int r = rowBase + (i >> (K == 128 ? 7 : 6));
        int k = i & (K - 1);
        Xs[i] = (r < nrows) ? x[(size_t)r * K + k] : 0.0f;
    }
    __syncthreads();
    const int lane = tid & 63;
    const int wave = tid >> 6;
    for (int rr = 0; rr < 4; ++rr) {
        int lr = wave * 4 + rr;
        int r = rowBase + lr;
        if (r < nrows) {
            float acc = 0.0f;
#pragma unroll
            for (int k = 0; k < K; ++k)
                acc = fmaf(Xs[lr * K + k], Ws[k * FD + lane], acc);
            out[(size_t)r * FD + lane] = acc * dinv[r];
        }
    }
}

// Pull aggregation + fused epilogue. One wave per node, lane = feature.
template <bool RELU>
__global__ void agg_fused(const int* __restrict__ rowptr, const int* __restrict__ csr_src,
                          const float* __restrict__ dinv, const float* __restrict__ h,
                          const float* __restrict__ b, float* __restrict__ out, int N) {
    int node = (blockIdx.x * blockDim.x + threadIdx.x) >> 6;
    int lane = threadIdx.x & 63;
    if (node >= N) return;
    int beg = rowptr[node], end = rowptr[node + 1];
    float acc = h[(size_t)node * FD + lane];  // self-loop (h already dinv-scaled)
    int j = beg;
    for (; j + 3 < end; j += 4) {
        int s0 = csr_src[j], s1 = csr_src[j + 1], s2 = csr_src[j + 2], s3 = csr_src[j + 3];
        float a0 = h[(size_t)s0 * FD + lane];
        float a1 = h[(size_t)s1 * FD + lane];
        float a2 = h[(size_t)s2 * FD + lane];
        float a3 = h[(size_t)s3 * FD + lane];
        acc += (a0 + a1) + (a2 + a3);
    }
    for (; j < end; ++j) acc += h[(size_t)csr_src[j] * FD + lane];
    float v = fmaf(dinv[node], acc, b[lane]);
    if (RELU) v = fmaxf(v, 0.0f);
    out[(size_t)node * FD + lane] = v;
}

extern "C" void kernel_launch(void* const* d_in, const int* in_sizes, int n_in,
                              void* d_out, int out_size, void* d_ws, size_t ws_size,
                              hipStream_t stream) {
    const float* x  = (const float*)d_in[0];
    const int*   ei = (const int*)d_in[1];
    const float* W1 = (const float*)d_in[2];
    const float* b1 = (const float*)d_in[3];
    const float* W2 = (const float*)d_in[4];
    const float* b2 = (const float*)d_in[5];
    const float* W3 = (const float*)d_in[6];
    const float* b3 = (const float*)d_in[7];
    float* out = (float*)d_out;

    const int N = in_sizes[0] / 128;   // 50000
    const int E = in_sizes[1] / 2;     // 800000
    const int* src = ei;
    const int* dst = ei + E;

    // workspace layout
    float* bufA   = (float*)d_ws;                   // N*FD
    float* bufB   = bufA + (size_t)N * FD;          // N*FD
    float* dinv   = bufB + (size_t)N * FD;          // N
    int*   cnt    = (int*)(dinv + N);               // N
    int*   rowptr = cnt + N;                        // N+1
    int*   cursor = rowptr + N + 1;                 // N
    int*   csr    = cursor + N;                     // E
    int*   bsum   = csr + E;                        // nScanBlk

    const int nScanBlk = (N + SCHUNK - 1) / SCHUNK;
    dim3 blk(256);
    dim3 gE((E + 255) / 256);
    dim3 gGemm((N + 15) / 16);
    dim3 gAgg(((size_t)N * 64 + 255) / 256);

    // CSR build
    hipMemsetAsync(cnt, 0, (size_t)N * sizeof(int), stream);
    count_dst<<<gE, blk, 0, stream>>>(dst, cnt, E);
    scan_partial<<<nScanBlk, blk, 0, stream>>>(cnt, bsum, N);
    scan_blocksums<<<1, 64, 0, stream>>>(bsum, nScanBlk);
    scan_final<<<nScanBlk, blk, 0, stream>>>(cnt, bsum, rowptr, cursor, dinv, N, E);
    build_csr<<<gE, blk, 0, stream>>>(src, dst, cursor, csr, E);

    // Layer 1: x(128) -> bufA -> agg -> bufB
    gemm_kernel<128><<<gGemm, blk, 0, stream>>>(x, W1, dinv, bufA, N);
    agg_fused<true><<<gAgg, blk, 0, stream>>>(rowptr, csr, dinv, bufA, b1, bufB, N);

    // Layer 2: bufB -> bufA -> agg -> bufB
    gemm_kernel<64><<<gGemm, blk, 0, stream>>>(bufB, W2, dinv, bufA, N);
    agg_fused<true><<<gAgg, blk, 0, stream>>>(rowptr, csr, dinv, bufA, b2, bufB, N);

    // Layer 3: bufB -> bufA -> agg -> out
    gemm_kernel<64><<<gGemm, blk, 0, stream>>>(bufB, W3, dinv, bufA, N);
    agg_fused<false><<<gAgg, blk, 0, stream>>>(rowptr, csr, dinv, bufA, b3, out, N);
}

// Round 5
// 267.099 us; speedup vs baseline: 2.6902x; 1.1769x over previous
//
#include <hip/hip_runtime.h>

// SparseGCN: 3-layer GCN, N=50000, E=800000, dims 128->64->64->64.
// dst-CSR built per call (multi-block scan), pull-aggregation with fused epilogue.
// GEMM: lane=row mapping; x per-lane from LDS (b128), W wave-uniform via scalar loads.

#define FD 64
#define SCHUNK 2048  // elements per scan block (256 thr x 8)

__global__ void count_dst(const int* __restrict__ dst, int* __restrict__ cnt, int E) {
    int e = blockIdx.x * blockDim.x + threadIdx.x;
    if (e < E) atomicAdd(&cnt[dst[e]], 1);
}

// A: per-block partial sums of cnt
__global__ void scan_partial(const int* __restrict__ cnt, int* __restrict__ bsum, int n) {
    __shared__ int wsum[4];
    const int tid = threadIdx.x, lane = tid & 63, wv = tid >> 6;
    int base = blockIdx.x * SCHUNK + tid * 8;
    int s = 0;
#pragma unroll
    for (int k = 0; k < 8; ++k) {
        int i = base + k;
        if (i < n) s += cnt[i];
    }
    for (int off = 1; off < 64; off <<= 1) s += __shfl_xor(s, off, 64);
    if (lane == 0) wsum[wv] = s;
    __syncthreads();
    if (tid == 0) bsum[blockIdx.x] = wsum[0] + wsum[1] + wsum[2] + wsum[3];
}

// B: exclusive scan of block sums (single wave)
__global__ void scan_blocksums(int* bsum, int nblk) {
    int lane = threadIdx.x;
    int carry = 0;
    for (int base = 0; base < nblk; base += 64) {
        int i = base + lane;
        int v = (i < nblk) ? bsum[i] : 0;
        int x = v;
        for (int off = 1; off < 64; off <<= 1) {
            int t = __shfl_up(x, off, 64);
            if (lane >= off) x += t;
        }
        if (i < nblk) bsum[i] = carry + x - v;
        carry += __shfl(x, 63, 64);
    }
}

// C: final scan: rowptr/cursor = exclusive prefix, dinv = rsqrt(cnt+1)
__global__ void scan_final(const int* __restrict__ cnt, const int* __restrict__ bsum,
                           int* __restrict__ rowptr, int* __restrict__ cursor,
                           float* __restrict__ dinv, int n, int E) {
    __shared__ int wofs[4];
    const int tid = threadIdx.x, lane = tid & 63, wv = tid >> 6;
    int base = blockIdx.x * SCHUNK + tid * 8;
    int vals[8];
    int s = 0;
#pragma unroll
    for (int k = 0; k < 8; ++k) {
        int i = base + k;
        vals[k] = (i < n) ? cnt[i] : 0;
        s += vals[k];
    }
    int x = s;
    for (int off = 1; off < 64; off <<= 1) {
        int t = __shfl_up(x, off, 64);
        if (lane >= off) x += t;
    }
    if (lane == 63) wofs[wv] = x;
    __syncthreads();
    int wex = 0;
    for (int i = 0; i < wv; ++i) wex += wofs[i];
    int run = (x - s) + wex + bsum[blockIdx.x];
#pragma unroll
    for (int k = 0; k < 8; ++k) {
        int i = base + k;
        if (i < n) {
            rowptr[i] = run;
            cursor[i] = run;
            dinv[i] = rsqrtf((float)(vals[k] + 1));
            run += vals[k];
        }
    }
    if (blockIdx.x == 0 && tid == 0) rowptr[n] = E;
}

__global__ void build_csr(const int* __restrict__ src, const int* __restrict__ dst,
                          int* __restrict__ cursor, int* __restrict__ csr_src, int E) {
    int e = blockIdx.x * blockDim.x + threadIdx.x;
    if (e < E) {
        int pos = atomicAdd(&cursor[dst[e]], 1);
        csr_src[pos] = src[e];
    }
}

// Dense h' = dinv[row] * (x @ W)   (x: nrows x K, W: K x 64)
// Block = 256 thr = 4 waves, 64 rows. lane = row; wave w owns columns [w*16, w*16+16).
// x row in LDS (pad +4 floats, 16B-aligned), read per-lane as float4.
// W[k][c] is wave-uniform -> readfirstlane'd index -> scalar loads (constant cache).
template <int K>
__global__ __launch_bounds__(256) void gemm_kernel(const float* __restrict__ x,
                                                   const float* __restrict__ W,
                                                   const float* __restrict__ dinv,
                                                   float* __restrict__ out, int nrows) {
    constexpr int KP = K + 4;       // row pad: keeps 16B alignment, spreads b128 slots
    constexpr int NC = K / 4;       // float4 chunks per row
    constexpr int YP = 68;          // output transpose pad
    __shared__ float Xs[64 * KP];   // reused as Ys[64][YP] for the store transpose
    const int tid = threadIdx.x;
    const int lane = tid & 63;
    const int rowBase = blockIdx.x * 64;

    // stage 64 x-rows -> LDS (coalesced float4 reads)
    for (int idx = tid; idx < 64 * NC; idx += 256) {
        int row = idx / NC, kc = idx % NC;
        int r = rowBase + row;
        float4 v = (r < nrows) ? *(const float4*)(x + (size_t)r * K + kc * 4)
                               : make_float4(0.f, 0.f, 0.f, 0.f);
        *(float4*)(&Xs[row * KP + kc * 4]) = v;
    }
    __syncthreads();

    const int c0 = __builtin_amdgcn_readfirstlane((tid >> 6) * 16);
    float acc[16];
#pragma unroll
    for (int i = 0; i < 16; ++i) acc[i] = 0.f;
    const float* Xrow = &Xs[lane * KP];

#pragma unroll 4
    for (int k = 0; k < K; k += 4) {
        float4 xv = *(const float4*)(Xrow + k);
        const float* wp = W + (size_t)k * FD + c0;   // uniform
#pragma unroll
        for (int ci = 0; ci < 16; ++ci) {
            acc[ci] = fmaf(xv.x, wp[ci], acc[ci]);
            acc[ci] = fmaf(xv.y, wp[FD + ci], acc[ci]);
            acc[ci] = fmaf(xv.z, wp[2 * FD + ci], acc[ci]);
            acc[ci] = fmaf(xv.w, wp[3 * FD + ci], acc[ci]);
        }
    }

    int r = rowBase + lane;
    float di = (r < nrows) ? dinv[r] : 0.f;
    __syncthreads();                 // all waves done reading Xs
    float* Ys = Xs;
#pragma unroll
    for (int ci = 0; ci < 16; ++ci) Ys[lane * YP + c0 + ci] = acc[ci] * di;
    __syncthreads();

    // coalesced store: 64 rows x 16 float4 segments = 1024 stores, 4 per thread
    for (int i = tid; i < 64 * 16; i += 256) {
        int row = i >> 4, cseg = i & 15;
        int rr = rowBase + row;
        if (rr < nrows) {
            float4 v = *(const float4*)(&Ys[row * YP + cseg * 4]);
            *(float4*)(out + (size_t)rr * FD + cseg * 4) = v;
        }
    }
}

// Pull aggregation + fused epilogue. One wave per node, lane = feature.
template <bool RELU>
__global__ void agg_fused(const int* __restrict__ rowptr, const int* __restrict__ csr_src,
                          const float* __restrict__ dinv, const float* __restrict__ h,
                          const float* __restrict__ b, float* __restrict__ out, int N) {
    int node = (blockIdx.x * blockDim.x + threadIdx.x) >> 6;
    int lane = threadIdx.x & 63;
    if (node >= N) return;
    int beg = rowptr[node], end = rowptr[node + 1];
    float acc = h[(size_t)node * FD + lane];  // self-loop (h already dinv-scaled)
    int j = beg;
    for (; j + 3 < end; j += 4) {
        int s0 = csr_src[j], s1 = csr_src[j + 1], s2 = csr_src[j + 2], s3 = csr_src[j + 3];
        float a0 = h[(size_t)s0 * FD + lane];
        float a1 = h[(size_t)s1 * FD + lane];
        float a2 = h[(size_t)s2 * FD + lane];
        float a3 = h[(size_t)s3 * FD + lane];
        acc += (a0 + a1) + (a2 + a3);
    }
    for (; j < end; ++j) acc += h[(size_t)csr_src[j] * FD + lane];
    float v = fmaf(dinv[node], acc, b[lane]);
    if (RELU) v = fmaxf(v, 0.0f);
    out[(size_t)node * FD + lane] = v;
}

extern "C" void kernel_launch(void* const* d_in, const int* in_sizes, int n_in,
                              void* d_out, int out_size, void* d_ws, size_t ws_size,
                              hipStream_t stream) {
    const float* x  = (const float*)d_in[0];
    const int*   ei = (const int*)d_in[1];
    const float* W1 = (const float*)d_in[2];
    const float* b1 = (const float*)d_in[3];
    const float* W2 = (const float*)d_in[4];
    const float* b2 = (const float*)d_in[5];
    const float* W3 = (const float*)d_in[6];
    const float* b3 = (const float*)d_in[7];
    float* out = (float*)d_out;

    const int N = in_sizes[0] / 128;   // 50000
    const int E = in_sizes[1] / 2;     // 800000
    const int* src = ei;
    const int* dst = ei + E;

    // workspace layout
    float* bufA   = (float*)d_ws;                   // N*FD
    float* bufB   = bufA + (size_t)N * FD;          // N*FD
    float* dinv   = bufB + (size_t)N * FD;          // N
    int*   cnt    = (int*)(dinv + N);               // N
    int*   rowptr = cnt + N;                        // N+1
    int*   cursor = rowptr + N + 1;                 // N
    int*   csr    = cursor + N;                     // E
    int*   bsum   = csr + E;                        // nScanBlk

    const int nScanBlk = (N + SCHUNK - 1) / SCHUNK;
    dim3 blk(256);
    dim3 gE((E + 255) / 256);
    dim3 gGemm((N + 63) / 64);
    dim3 gAgg(((size_t)N * 64 + 255) / 256);

    // CSR build
    hipMemsetAsync(cnt, 0, (size_t)N * sizeof(int), stream);
    count_dst<<<gE, blk, 0, stream>>>(dst, cnt, E);
    scan_partial<<<nScanBlk, blk, 0, stream>>>(cnt, bsum, N);
    scan_blocksums<<<1, 64, 0, stream>>>(bsum, nScanBlk);
    scan_final<<<nScanBlk, blk, 0, stream>>>(cnt, bsum, rowptr, cursor, dinv, N, E);
    build_csr<<<gE, blk, 0, stream>>>(src, dst, cursor, csr, E);

    // Layer 1: x(128) -> bufA -> agg -> bufB
    gemm_kernel<128><<<gGemm, blk, 0, stream>>>(x, W1, dinv, bufA, N);
    agg_fused<true><<<gAgg, blk, 0, stream>>>(rowptr, csr, dinv, bufA, b1, bufB, N);

    // Layer 2: bufB -> bufA -> agg -> bufB
    gemm_kernel<64><<<gGemm, blk, 0, stream>>>(bufB, W2, dinv, bufA, N);
    agg_fused<true><<<gAgg, blk, 0, stream>>>(rowptr, csr, dinv, bufA, b2, bufB, N);

    // Layer 3: bufB -> bufA -> agg -> out
    gemm_kernel<64><<<gGemm, blk, 0, stream>>>(bufB, W3, dinv, bufA, N);
    agg_fused<false><<<gAgg, blk, 0, stream>>>(rowptr, csr, dinv, bufA, b3, out, N);
}

// Round 6
// 230.755 us; speedup vs baseline: 3.1139x; 1.1575x over previous
//
#include <hip/hip_runtime.h>

// SparseGCN: 3-layer GCN, N=50000, E=800000, dims 128->64->64->64.
// dst-CSR per call (multi-block scan), pull-aggregation 4-nodes-per-wave,
// GEMM lane=row with scalar-pipe W. gemm1 overlapped with build_csr (fat kernel).

#define FD 64
#define SCHUNK 2048  // elements per scan block (256 thr x 8)

__global__ void count_dst(const int* __restrict__ dst, int* __restrict__ cnt, int E) {
    int e = blockIdx.x * blockDim.x + threadIdx.x;
    if (e < E) atomicAdd(&cnt[dst[e]], 1);
}

// A: per-block partial sums of cnt
__global__ void scan_partial(const int* __restrict__ cnt, int* __restrict__ bsum, int n) {
    __shared__ int wsum[4];
    const int tid = threadIdx.x, lane = tid & 63, wv = tid >> 6;
    int base = blockIdx.x * SCHUNK + tid * 8;
    int s = 0;
#pragma unroll
    for (int k = 0; k < 8; ++k) {
        int i = base + k;
        if (i < n) s += cnt[i];
    }
    for (int off = 1; off < 64; off <<= 1) s += __shfl_xor(s, off, 64);
    if (lane == 0) wsum[wv] = s;
    __syncthreads();
    if (tid == 0) bsum[blockIdx.x] = wsum[0] + wsum[1] + wsum[2] + wsum[3];
}

// B: exclusive scan of block sums (single wave)
__global__ void scan_blocksums(int* bsum, int nblk) {
    int lane = threadIdx.x;
    int carry = 0;
    for (int base = 0; base < nblk; base += 64) {
        int i = base + lane;
        int v = (i < nblk) ? bsum[i] : 0;
        int x = v;
        for (int off = 1; off < 64; off <<= 1) {
            int t = __shfl_up(x, off, 64);
            if (lane >= off) x += t;
        }
        if (i < nblk) bsum[i] = carry + x - v;
        carry += __shfl(x, 63, 64);
    }
}

// C: final scan: rowptr/cursor = exclusive prefix, dinv = rsqrt(cnt+1)
__global__ void scan_final(const int* __restrict__ cnt, const int* __restrict__ bsum,
                           int* __restrict__ rowptr, int* __restrict__ cursor,
                           float* __restrict__ dinv, int n, int E) {
    __shared__ int wofs[4];
    const int tid = threadIdx.x, lane = tid & 63, wv = tid >> 6;
    int base = blockIdx.x * SCHUNK + tid * 8;
    int vals[8];
    int s = 0;
#pragma unroll
    for (int k = 0; k < 8; ++k) {
        int i = base + k;
        vals[k] = (i < n) ? cnt[i] : 0;
        s += vals[k];
    }
    int x = s;
    for (int off = 1; off < 64; off <<= 1) {
        int t = __shfl_up(x, off, 64);
        if (lane >= off) x += t;
    }
    if (lane == 63) wofs[wv] = x;
    __syncthreads();
    int wex = 0;
    for (int i = 0; i < wv; ++i) wex += wofs[i];
    int run = (x - s) + wex + bsum[blockIdx.x];
#pragma unroll
    for (int k = 0; k < 8; ++k) {
        int i = base + k;
        if (i < n) {
            rowptr[i] = run;
            cursor[i] = run;
            dinv[i] = rsqrtf((float)(vals[k] + 1));
            run += vals[k];
        }
    }
    if (blockIdx.x == 0 && tid == 0) rowptr[n] = E;
}

// Dense h' = dinv[row] * (x @ W) body. Block bid covers rows [bid*64, bid*64+64).
// lane=row; x per-lane from LDS; W wave-uniform -> scalar loads (constant cache).
template <int K>
__device__ __forceinline__ void gemm_body(int bid, const float* __restrict__ x,
                                          const float* __restrict__ W,
                                          const float* __restrict__ dinv,
                                          float* __restrict__ out, int nrows,
                                          float* Xs /* >= 64*(K+4) floats */) {
    constexpr int KP = K + 4;
    constexpr int NC = K / 4;
    constexpr int YP = 68;
    const int tid = threadIdx.x;
    const int lane = tid & 63;
    const int rowBase = bid * 64;

    for (int idx = tid; idx < 64 * NC; idx += 256) {
        int row = idx / NC, kc = idx % NC;
        int r = rowBase + row;
        float4 v = (r < nrows) ? *(const float4*)(x + (size_t)r * K + kc * 4)
                               : make_float4(0.f, 0.f, 0.f, 0.f);
        *(float4*)(&Xs[row * KP + kc * 4]) = v;
    }
    __syncthreads();

    const int c0 = __builtin_amdgcn_readfirstlane((tid >> 6) * 16);
    float acc[16];
#pragma unroll
    for (int i = 0; i < 16; ++i) acc[i] = 0.f;
    const float* Xrow = &Xs[lane * KP];

#pragma unroll 4
    for (int k = 0; k < K; k += 4) {
        float4 xv = *(const float4*)(Xrow + k);
        const float* wp = W + (size_t)k * FD + c0;   // uniform
#pragma unroll
        for (int ci = 0; ci < 16; ++ci) {
            acc[ci] = fmaf(xv.x, wp[ci], acc[ci]);
            acc[ci] = fmaf(xv.y, wp[FD + ci], acc[ci]);
            acc[ci] = fmaf(xv.z, wp[2 * FD + ci], acc[ci]);
            acc[ci] = fmaf(xv.w, wp[3 * FD + ci], acc[ci]);
        }
    }

    int r = rowBase + lane;
    float di = (r < nrows) ? dinv[r] : 0.f;
    __syncthreads();
    float* Ys = Xs;
#pragma unroll
    for (int ci = 0; ci < 16; ++ci) Ys[lane * YP + c0 + ci] = acc[ci] * di;
    __syncthreads();

    for (int i = tid; i < 64 * 16; i += 256) {
        int row = i >> 4, cseg = i & 15;
        int rr = rowBase + row;
        if (rr < nrows) {
            float4 v = *(const float4*)(&Ys[row * YP + cseg * 4]);
            *(float4*)(out + (size_t)rr * FD + cseg * 4) = v;
        }
    }
}

template <int K>
__global__ __launch_bounds__(256) void gemm_kernel(const float* __restrict__ x,
                                                   const float* __restrict__ W,
                                                   const float* __restrict__ dinv,
                                                   float* __restrict__ out, int nrows) {
    __shared__ float Xs[64 * (K + 4)];
    gemm_body<K>(blockIdx.x, x, W, dinv, out, nrows, Xs);
}

// Fat kernel: blocks [0, nGemmBlk) run gemm1 (VALU-bound), the rest run
// build_csr's scatter (HBM-write-bound) -- independent work, overlapped.
__global__ __launch_bounds__(256) void fused_gemm1_build(
    const float* __restrict__ x, const float* __restrict__ W1,
    const float* __restrict__ dinv, float* __restrict__ bufA, int nrows,
    const int* __restrict__ src, const int* __restrict__ dst,
    int* __restrict__ cursor, int* __restrict__ csr, int E, int nGemmBlk) {
    __shared__ float Xs[64 * 132];  // K=128 staging
    int bid = blockIdx.x;
    if (bid < nGemmBlk) {
        gemm_body<128>(bid, x, W1, dinv, bufA, nrows, Xs);
    } else {
        int e = (bid - nGemmBlk) * 256 + threadIdx.x;
        if (e < E) {
            int pos = atomicAdd(&cursor[dst[e]], 1);
            csr[pos] = src[e];
        }
    }
}

// Pull aggregation + fused epilogue. 4 nodes per wave: 16 lanes x float4 each.
// One load instruction fetches 4 edges' 256B rows -> 4x shorter latency chain/node.
template <bool RELU>
__global__ __launch_bounds__(256) void agg_fused(
    const int* __restrict__ rowptr, const int* __restrict__ csr_src,
    const float* __restrict__ dinv, const float* __restrict__ h,
    const float* __restrict__ b, float* __restrict__ out, int N) {
    int wid = (blockIdx.x * blockDim.x + threadIdx.x) >> 6;
    int lane = threadIdx.x & 63;
    int l = lane & 15;                 // float4 segment within row
    int node = wid * 4 + (lane >> 4);
    bool valid = node < N;
    int nd = valid ? node : N - 1;
    int beg = rowptr[nd];
    int end = valid ? rowptr[nd + 1] : beg;
    const float4* __restrict__ h4 = (const float4*)h;
    float4 acc = h4[(size_t)nd * 16 + l];   // self-loop (h already dinv-scaled)
    int j = beg;
    for (; j + 3 < end; j += 4) {
        int s0 = csr_src[j], s1 = csr_src[j + 1], s2 = csr_src[j + 2], s3 = csr_src[j + 3];
        float4 a0 = h4[(size_t)s0 * 16 + l];
        float4 a1 = h4[(size_t)s1 * 16 + l];
        float4 a2 = h4[(size_t)s2 * 16 + l];
        float4 a3 = h4[(size_t)s3 * 16 + l];
        acc.x += (a0.x + a1.x) + (a2.x + a3.x);
        acc.y += (a0.y + a1.y) + (a2.y + a3.y);
        acc.z += (a0.z + a1.z) + (a2.z + a3.z);
        acc.w += (a0.w + a1.w) + (a2.w + a3.w);
    }
    for (; j < end; ++j) {
        int s = csr_src[j];
        float4 a = h4[(size_t)s * 16 + l];
        acc.x += a.x; acc.y += a.y; acc.z += a.z; acc.w += a.w;
    }
    float di = dinv[nd];
    float4 bb = ((const float4*)b)[l];
    float4 v;
    v.x = fmaf(di, acc.x, bb.x);
    v.y = fmaf(di, acc.y, bb.y);
    v.z = fmaf(di, acc.z, bb.z);
    v.w = fmaf(di, acc.w, bb.w);
    if (RELU) {
        v.x = fmaxf(v.x, 0.f); v.y = fmaxf(v.y, 0.f);
        v.z = fmaxf(v.z, 0.f); v.w = fmaxf(v.w, 0.f);
    }
    if (valid) ((float4*)out)[(size_t)node * 16 + l] = v;
}

extern "C" void kernel_launch(void* const* d_in, const int* in_sizes, int n_in,
                              void* d_out, int out_size, void* d_ws, size_t ws_size,
                              hipStream_t stream) {
    const float* x  = (const float*)d_in[0];
    const int*   ei = (const int*)d_in[1];
    const float* W1 = (const float*)d_in[2];
    const float* b1 = (const float*)d_in[3];
    const float* W2 = (const float*)d_in[4];
    const float* b2 = (const float*)d_in[5];
    const float* W3 = (const float*)d_in[6];
    const float* b3 = (const float*)d_in[7];
    float* out = (float*)d_out;

    const int N = in_sizes[0] / 128;   // 50000
    const int E = in_sizes[1] / 2;     // 800000
    const int* src = ei;
    const int* dst = ei + E;

    // workspace layout
    float* bufA   = (float*)d_ws;                   // N*FD
    float* bufB   = bufA + (size_t)N * FD;          // N*FD
    float* dinv   = bufB + (size_t)N * FD;          // N
    int*   cnt    = (int*)(dinv + N);               // N
    int*   rowptr = cnt + N;                        // N+1
    int*   cursor = rowptr + N + 1;                 // N
    int*   csr    = cursor + N;                     // E
    int*   bsum   = csr + E;                        // nScanBlk

    const int nScanBlk = (N + SCHUNK - 1) / SCHUNK;
    const int nGemmBlk = (N + 63) / 64;
    const int nBuildBlk = (E + 255) / 256;
    dim3 blk(256);
    dim3 gE((E + 255) / 256);
    dim3 gGemm(nGemmBlk);
    dim3 gAgg((N + 15) / 16);   // 4 nodes/wave, 4 waves/block

    // CSR build prefix
    hipMemsetAsync(cnt, 0, (size_t)N * sizeof(int), stream);
    count_dst<<<gE, blk, 0, stream>>>(dst, cnt, E);
    scan_partial<<<nScanBlk, blk, 0, stream>>>(cnt, bsum, N);
    scan_blocksums<<<1, 64, 0, stream>>>(bsum, nScanBlk);
    scan_final<<<nScanBlk, blk, 0, stream>>>(cnt, bsum, rowptr, cursor, dinv, N, E);

    // Layer 1 GEMM overlapped with CSR scatter
    fused_gemm1_build<<<dim3(nGemmBlk + nBuildBlk), blk, 0, stream>>>(
        x, W1, dinv, bufA, N, src, dst, cursor, csr, E, nGemmBlk);
    agg_fused<true><<<gAgg, blk, 0, stream>>>(rowptr, csr, dinv, bufA, b1, bufB, N);

    // Layer 2: bufB -> bufA -> agg -> bufB
    gemm_kernel<64><<<gGemm, blk, 0, stream>>>(bufB, W2, dinv, bufA, N);
    agg_fused<true><<<gAgg, blk, 0, stream>>>(rowptr, csr, dinv, bufA, b2, bufB, N);

    // Layer 3: bufB -> bufA -> agg -> out
    gemm_kernel<64><<<gGemm, blk, 0, stream>>>(bufB, W3, dinv, bufA, N);
    agg_fused<false><<<gAgg, blk, 0, stream>>>(rowptr, csr, dinv, bufA, b3, out, N);
}

// Round 7
// 182.931 us; speedup vs baseline: 3.9280x; 1.2614x over previous
//
#include <hip/hip_runtime.h>

// SparseGCN: 3-layer GCN, N=50000, E=800000, dims 128->64->64->64.
// dst-CSR per call; pull-aggregation gathers bf16 h' rows (halved gather bytes),
// f32 accumulate. GEMM lane=row, scalar-pipe W, bf16-packed epilogue.
// gemm1 overlapped with CSR scatter (fat kernel).

#define FD 64
#define SCHUNK 2048

typedef unsigned short ushort_t;
typedef unsigned int uint_t;

__device__ __forceinline__ ushort_t f2bf(float f) {
    uint_t u = __float_as_uint(f);
    u = (u + 0x7fffu + ((u >> 16) & 1u)) >> 16;   // RNE
    return (ushort_t)u;
}
__device__ __forceinline__ uint_t pack2bf(float f0, float f1) {
    return (uint_t)f2bf(f0) | ((uint_t)f2bf(f1) << 16);
}

__global__ void count_dst(const int* __restrict__ dst, int* __restrict__ cnt, int E) {
    int e = blockIdx.x * blockDim.x + threadIdx.x;
    if (e < E) atomicAdd(&cnt[dst[e]], 1);
}

__global__ void scan_partial(const int* __restrict__ cnt, int* __restrict__ bsum, int n) {
    __shared__ int wsum[4];
    const int tid = threadIdx.x, lane = tid & 63, wv = tid >> 6;
    int base = blockIdx.x * SCHUNK + tid * 8;
    int s = 0;
#pragma unroll
    for (int k = 0; k < 8; ++k) {
        int i = base + k;
        if (i < n) s += cnt[i];
    }
    for (int off = 1; off < 64; off <<= 1) s += __shfl_xor(s, off, 64);
    if (lane == 0) wsum[wv] = s;
    __syncthreads();
    if (tid == 0) bsum[blockIdx.x] = wsum[0] + wsum[1] + wsum[2] + wsum[3];
}

__global__ void scan_blocksums(int* bsum, int nblk) {
    int lane = threadIdx.x;
    int carry = 0;
    for (int base = 0; base < nblk; base += 64) {
        int i = base + lane;
        int v = (i < nblk) ? bsum[i] : 0;
        int x = v;
        for (int off = 1; off < 64; off <<= 1) {
            int t = __shfl_up(x, off, 64);
            if (lane >= off) x += t;
        }
        if (i < nblk) bsum[i] = carry + x - v;
        carry += __shfl(x, 63, 64);
    }
}

__global__ void scan_final(const int* __restrict__ cnt, const int* __restrict__ bsum,
                           int* __restrict__ rowptr, int* __restrict__ cursor,
                           float* __restrict__ dinv, int n, int E) {
    __shared__ int wofs[4];
    const int tid = threadIdx.x, lane = tid & 63, wv = tid >> 6;
    int base = blockIdx.x * SCHUNK + tid * 8;
    int vals[8];
    int s = 0;
#pragma unroll
    for (int k = 0; k < 8; ++k) {
        int i = base + k;
        vals[k] = (i < n) ? cnt[i] : 0;
        s += vals[k];
    }
    int x = s;
    for (int off = 1; off < 64; off <<= 1) {
        int t = __shfl_up(x, off, 64);
        if (lane >= off) x += t;
    }
    if (lane == 63) wofs[wv] = x;
    __syncthreads();
    int wex = 0;
    for (int i = 0; i < wv; ++i) wex += wofs[i];
    int run = (x - s) + wex + bsum[blockIdx.x];
#pragma unroll
    for (int k = 0; k < 8; ++k) {
        int i = base + k;
        if (i < n) {
            rowptr[i] = run;
            cursor[i] = run;
            dinv[i] = rsqrtf((float)(vals[k] + 1));
            run += vals[k];
        }
    }
    if (blockIdx.x == 0 && tid == 0) rowptr[n] = E;
}

// Dense h' = dinv[row]*(x@W), OUTPUT PACKED BF16. Block covers 64 rows.
// lane=row; x per-lane from LDS; W wave-uniform -> scalar loads.
template <int K>
__device__ __forceinline__ void gemm_body(int bid, const float* __restrict__ x,
                                          const float* __restrict__ W,
                                          const float* __restrict__ dinv,
                                          ushort_t* __restrict__ out, int nrows,
                                          float* Xs /* >= 64*(K+4) floats */) {
    constexpr int KP = K + 4;
    constexpr int NC = K / 4;
    constexpr int YP = 68;
    const int tid = threadIdx.x;
    const int lane = tid & 63;
    const int rowBase = bid * 64;

    for (int idx = tid; idx < 64 * NC; idx += 256) {
        int row = idx / NC, kc = idx % NC;
        int r = rowBase + row;
        float4 v = (r < nrows) ? *(const float4*)(x + (size_t)r * K + kc * 4)
                               : make_float4(0.f, 0.f, 0.f, 0.f);
        *(float4*)(&Xs[row * KP + kc * 4]) = v;
    }
    __syncthreads();

    const int c0 = __builtin_amdgcn_readfirstlane((tid >> 6) * 16);
    float acc[16];
#pragma unroll
    for (int i = 0; i < 16; ++i) acc[i] = 0.f;
    const float* Xrow = &Xs[lane * KP];

#pragma unroll 4
    for (int k = 0; k < K; k += 4) {
        float4 xv = *(const float4*)(Xrow + k);
        const float* wp = W + (size_t)k * FD + c0;   // uniform
#pragma unroll
        for (int ci = 0; ci < 16; ++ci) {
            acc[ci] = fmaf(xv.x, wp[ci], acc[ci]);
            acc[ci] = fmaf(xv.y, wp[FD + ci], acc[ci]);
            acc[ci] = fmaf(xv.z, wp[2 * FD + ci], acc[ci]);
            acc[ci] = fmaf(xv.w, wp[3 * FD + ci], acc[ci]);
        }
    }

    int r = rowBase + lane;
    float di = (r < nrows) ? dinv[r] : 0.f;
    __syncthreads();
    float* Ys = Xs;
#pragma unroll
    for (int ci = 0; ci < 16; ++ci) Ys[lane * YP + c0 + ci] = acc[ci] * di;
    __syncthreads();

    // pack to bf16, coalesced uint2 (4 bf16) stores: 64 rows x 16 segs
    for (int i = tid; i < 64 * 16; i += 256) {
        int row = i >> 4, seg = i & 15;
        int rr = rowBase + row;
        if (rr < nrows) {
            float4 v = *(const float4*)(&Ys[row * YP + seg * 4]);
            uint2 p;
            p.x = pack2bf(v.x, v.y);
            p.y = pack2bf(v.z, v.w);
            *(uint2*)(out + (size_t)rr * FD + seg * 4) = p;
        }
    }
}

template <int K>
__global__ __launch_bounds__(256) void gemm_kernel(const float* __restrict__ x,
                                                   const float* __restrict__ W,
                                                   const float* __restrict__ dinv,
                                                   ushort_t* __restrict__ out, int nrows) {
    __shared__ float Xs[64 * (K + 4)];
    gemm_body<K>(blockIdx.x, x, W, dinv, out, nrows, Xs);
}

// Fat kernel: gemm1 blocks (VALU-bound) + CSR scatter blocks (HBM-write-bound).
__global__ __launch_bounds__(256) void fused_gemm1_build(
    const float* __restrict__ x, const float* __restrict__ W1,
    const float* __restrict__ dinv, ushort_t* __restrict__ hB, int nrows,
    const int* __restrict__ src, const int* __restrict__ dst,
    int* __restrict__ cursor, int* __restrict__ csr, int E, int nGemmBlk) {
    __shared__ float Xs[64 * 132];
    int bid = blockIdx.x;
    if (bid < nGemmBlk) {
        gemm_body<128>(bid, x, W1, dinv, hB, nrows, Xs);
    } else {
        int e = (bid - nGemmBlk) * 256 + threadIdx.x;
        if (e < E) {
            int pos = atomicAdd(&cursor[dst[e]], 1);
            csr[pos] = src[e];
        }
    }
}

__device__ __forceinline__ void bf8_acc(uint4 a, float* acc) {
    acc[0] += __uint_as_float(a.x << 16);
    acc[1] += __uint_as_float(a.x & 0xffff0000u);
    acc[2] += __uint_as_float(a.y << 16);
    acc[3] += __uint_as_float(a.y & 0xffff0000u);
    acc[4] += __uint_as_float(a.z << 16);
    acc[5] += __uint_as_float(a.z & 0xffff0000u);
    acc[6] += __uint_as_float(a.w << 16);
    acc[7] += __uint_as_float(a.w & 0xffff0000u);
}

// Pull aggregation + fused epilogue. 8 nodes/wave: 8 lanes x 8 bf16 features each.
// Gathers 128B/row (bf16), accumulates f32, writes f32.
template <bool RELU>
__global__ __launch_bounds__(256) void agg_fused(
    const int* __restrict__ rowptr, const int* __restrict__ csr_src,
    const float* __restrict__ dinv, const ushort_t* __restrict__ h,
    const float* __restrict__ b, float* __restrict__ out, int N) {
    int wid = (blockIdx.x * blockDim.x + threadIdx.x) >> 6;
    int lane = threadIdx.x & 63;
    int l8 = lane & 7;                  // 16B segment (8 bf16) within row
    int node = wid * 8 + (lane >> 3);
    bool valid = node < N;
    int nd = valid ? node : N - 1;
    int beg = rowptr[nd];
    int end = valid ? rowptr[nd + 1] : beg;
    const uint4* __restrict__ h4 = (const uint4*)h;   // row = 8 uint4
    float acc[8];
#pragma unroll
    for (int k = 0; k < 8; ++k) acc[k] = 0.f;
    bf8_acc(h4[(size_t)nd * 8 + l8], acc);            // self-loop
    int j = beg;
    for (; j + 3 < end; j += 4) {
        int s0 = csr_src[j], s1 = csr_src[j + 1], s2 = csr_src[j + 2], s3 = csr_src[j + 3];
        uint4 a0 = h4[(size_t)s0 * 8 + l8];
        uint4 a1 = h4[(size_t)s1 * 8 + l8];
        uint4 a2 = h4[(size_t)s2 * 8 + l8];
        uint4 a3 = h4[(size_t)s3 * 8 + l8];
        bf8_acc(a0, acc); bf8_acc(a1, acc); bf8_acc(a2, acc); bf8_acc(a3, acc);
    }
    for (; j < end; ++j) bf8_acc(h4[(size_t)csr_src[j] * 8 + l8], acc);

    float di = dinv[nd];
    float4 b0 = *(const float4*)(b + l8 * 8);
    float4 b1 = *(const float4*)(b + l8 * 8 + 4);
    float4 v0, v1;
    v0.x = fmaf(di, acc[0], b0.x); v0.y = fmaf(di, acc[1], b0.y);
    v0.z = fmaf(di, acc[2], b0.z); v0.w = fmaf(di, acc[3], b0.w);
    v1.x = fmaf(di, acc[4], b1.x); v1.y = fmaf(di, acc[5], b1.y);
    v1.z = fmaf(di, acc[6], b1.z); v1.w = fmaf(di, acc[7], b1.w);
    if (RELU) {
        v0.x = fmaxf(v0.x, 0.f); v0.y = fmaxf(v0.y, 0.f);
        v0.z = fmaxf(v0.z, 0.f); v0.w = fmaxf(v0.w, 0.f);
        v1.x = fmaxf(v1.x, 0.f); v1.y = fmaxf(v1.y, 0.f);
        v1.z = fmaxf(v1.z, 0.f); v1.w = fmaxf(v1.w, 0.f);
    }
    if (valid) {
        float* op = out + (size_t)node * FD + l8 * 8;
        *(float4*)op = v0;
        *(float4*)(op + 4) = v1;
    }
}

extern "C" void kernel_launch(void* const* d_in, const int* in_sizes, int n_in,
                              void* d_out, int out_size, void* d_ws, size_t ws_size,
                              hipStream_t stream) {
    const float* x  = (const float*)d_in[0];
    const int*   ei = (const int*)d_in[1];
    const float* W1 = (const float*)d_in[2];
    const float* b1 = (const float*)d_in[3];
    const float* W2 = (const float*)d_in[4];
    const float* b2 = (const float*)d_in[5];
    const float* W3 = (const float*)d_in[6];
    const float* b3 = (const float*)d_in[7];
    float* out = (float*)d_out;

    const int N = in_sizes[0] / 128;   // 50000
    const int E = in_sizes[1] / 2;     // 800000
    const int* src = ei;
    const int* dst = ei + E;

    // workspace layout
    float*    f1   = (float*)d_ws;                      // N*64 f32 (agg out / gemm in)
    ushort_t* hB   = (ushort_t*)(f1 + (size_t)N * FD);  // N*64 bf16 (gemm out / gather src)
    float*    dinv = (float*)(hB + (size_t)N * FD);     // N
    int*      cnt  = (int*)(dinv + N);                  // N
    int*   rowptr  = cnt + N;                           // N+1
    int*   cursor  = rowptr + N + 1;                    // N
    int*   csr     = cursor + N;                        // E
    int*   bsum    = csr + E;                           // nScanBlk

    const int nScanBlk = (N + SCHUNK - 1) / SCHUNK;
    const int nGemmBlk = (N + 63) / 64;
    const int nBuildBlk = (E + 255) / 256;
    dim3 blk(256);
    dim3 gE((E + 255) / 256);
    dim3 gGemm(nGemmBlk);
    dim3 gAgg((N + 31) / 32);   // 8 nodes/wave, 4 waves/block

    // CSR prefix
    hipMemsetAsync(cnt, 0, (size_t)N * sizeof(int), stream);
    count_dst<<<gE, blk, 0, stream>>>(dst, cnt, E);
    scan_partial<<<nScanBlk, blk, 0, stream>>>(cnt, bsum, N);
    scan_blocksums<<<1, 64, 0, stream>>>(bsum, nScanBlk);
    scan_final<<<nScanBlk, blk, 0, stream>>>(cnt, bsum, rowptr, cursor, dinv, N, E);

    // Layer 1 GEMM overlapped with CSR scatter
    fused_gemm1_build<<<dim3(nGemmBlk + nBuildBlk), blk, 0, stream>>>(
        x, W1, dinv, hB, N, src, dst, cursor, csr, E, nGemmBlk);
    agg_fused<true><<<gAgg, blk, 0, stream>>>(rowptr, csr, dinv, hB, b1, f1, N);

    // Layer 2
    gemm_kernel<64><<<gGemm, blk, 0, stream>>>(f1, W2, dinv, hB, N);
    agg_fused<true><<<gAgg, blk, 0, stream>>>(rowptr, csr, dinv, hB, b2, f1, N);

    // Layer 3
    gemm_kernel<64><<<gGemm, blk, 0, stream>>>(f1, W3, dinv, hB, N);
    agg_fused<false><<<gAgg, blk, 0, stream>>>(rowptr, csr, dinv, hB, b3, out, N);
}

// Round 9
// 147.661 us; speedup vs baseline: 4.8662x; 1.2389x over previous
//
#include <hip/hip_runtime.h>

// SparseGCN: 3-layer GCN, N=50000, E=800000, dims 128->64->64->64.
// CSR build via bucketed 2-pass counting sort (bucket = dst>>8):
//   P0 bucket histogram -> S0 scan -> P1 two-pass bin-scatter (rank recomputed,
//   no cross-pass register state) -> P2 per-bucket sort (direct csr scatter,
//   8KB/bucket region -> L2-absorbed).
// Pull-aggregation gathers bf16 h' rows; GEMM lane=row with scalar-pipe W.

#define FD 64
#define P1CHUNK 4096  // edges per scatter block (256 thr x 16)

typedef unsigned short ushort_t;
typedef unsigned int uint_t;

__device__ __forceinline__ ushort_t f2bf(float f) {
    uint_t u = __float_as_uint(f);
    u = (u + 0x7fffu + ((u >> 16) & 1u)) >> 16;  // RNE
    return (ushort_t)u;
}
__device__ __forceinline__ uint_t pack2bf(float f0, float f1) {
    return (uint_t)f2bf(f0) | ((uint_t)f2bf(f1) << 16);
}

// P0: per-bucket edge counts (bucket = dst>>8). LDS-first histogram.
__global__ __launch_bounds__(256) void bucket_count(const int* __restrict__ dst,
                                                    int* __restrict__ bucketCnt, int E) {
    __shared__ int hist[256];
    int tid = threadIdx.x;
    hist[tid] = 0;
    __syncthreads();
    int base = blockIdx.x * P1CHUNK;
#pragma unroll
    for (int k = 0; k < 16; ++k) {
        int e = base + k * 256 + tid;
        if (e < E) atomicAdd(&hist[dst[e] >> 8], 1);
    }
    __syncthreads();
    int h = hist[tid];
    if (h) atomicAdd(&bucketCnt[tid], h);  // tid>=NB has h==0 (dst < N)
}

// S0: exclusive scan of NB (<=256) bucket counts -> bucketBase, bucketCursor.
__global__ __launch_bounds__(256) void scan_buckets(const int* __restrict__ bucketCnt,
                                                    int* __restrict__ bucketBase,
                                                    int* __restrict__ bucketCursor,
                                                    int* __restrict__ rowptr,
                                                    int NB, int N, int E) {
    __shared__ int wsum[4];
    int tid = threadIdx.x, lane = tid & 63, wv = tid >> 6;
    int v = (tid < NB) ? bucketCnt[tid] : 0;
    int x = v;
    for (int off = 1; off < 64; off <<= 1) {
        int t = __shfl_up(x, off, 64);
        if (lane >= off) x += t;
    }
    if (lane == 63) wsum[wv] = x;
    __syncthreads();
    int wex = 0;
    for (int i = 0; i < wv; ++i) wex += wsum[i];
    int excl = wex + x - v;
    if (tid < NB) { bucketBase[tid] = excl; bucketCursor[tid] = excl; }
    if (tid == 0) { bucketBase[NB] = E; rowptr[N] = E; }
}

// P1: two-pass bin-scatter. Pass 1: LDS histogram. Reserve contiguous bucket
// segments. Pass 2: recompute rank with a fresh LDS cursor, write immediately.
// Every staged slot written exactly once by construction.
__global__ __launch_bounds__(256) void bin_scatter(const int* __restrict__ src,
                                                   const int* __restrict__ dst,
                                                   int* __restrict__ bucketCursor,
                                                   uint_t* __restrict__ staged, int E) {
    __shared__ int hist[256];
    __shared__ int gbase[256];
    int tid = threadIdx.x;
    hist[tid] = 0;
    __syncthreads();
    int base = blockIdx.x * P1CHUNK;
#pragma unroll
    for (int k = 0; k < 16; ++k) {
        int e = base + k * 256 + tid;
        if (e < E) atomicAdd(&hist[dst[e] >> 8], 1);
    }
    __syncthreads();
    int h = hist[tid];  // own slot read; own slot cleared below (same thread)
    gbase[tid] = h ? atomicAdd(&bucketCursor[tid], h) : 0;
    hist[tid] = 0;      // becomes pass-2 local cursor
    __syncthreads();
#pragma unroll
    for (int k = 0; k < 16; ++k) {
        int e = base + k * 256 + tid;
        if (e < E) {
            int s = src[e], d = dst[e];
            int b = d >> 8;
            int r = atomicAdd(&hist[b], 1);  // r < h(b) of this block
            staged[gbase[b] + r] = (uint_t)s | ((uint_t)(d & 255) << 16);
        }
    }
}

// P2: per-bucket counting sort. rowptr/dinv slices coalesced; csr scatter is
// confined to this bucket's ~8KB region (L2-absorbed).
__global__ __launch_bounds__(256) void bucket_sort(const uint_t* __restrict__ staged,
                                                   const int* __restrict__ bucketBase,
                                                   int* __restrict__ rowptr,
                                                   float* __restrict__ dinv,
                                                   ushort_t* __restrict__ csr, int N) {
    __shared__ int ncnt[256];
    __shared__ int nrp[256];
    __shared__ int wsum[4];
    int tid = threadIdx.x, lane = tid & 63, wv = tid >> 6;
    int b = blockIdx.x;
    int gbeg = bucketBase[b], gend = bucketBase[b + 1];
    int cntE = gend - gbeg;
    ncnt[tid] = 0;
    __syncthreads();
    for (int i = tid; i < cntE; i += 256)
        atomicAdd(&ncnt[(staged[gbeg + i] >> 16) & 255], 1);
    __syncthreads();
    int v = ncnt[tid];
    int x = v;
    for (int off = 1; off < 64; off <<= 1) {
        int t = __shfl_up(x, off, 64);
        if (lane >= off) x += t;
    }
    if (lane == 63) wsum[wv] = x;
    __syncthreads();
    int wex = 0;
    for (int i = 0; i < wv; ++i) wex += wsum[i];
    int excl = wex + x - v;
    nrp[tid] = excl;
    int node = b * 256 + tid;
    if (node < N) dinv[node] = rsqrtf((float)(v + 1));
    if (node <= N) rowptr[node] = gbeg + excl;
    ncnt[tid] = 0;  // reuse as per-node cursor
    __syncthreads();
    for (int i = tid; i < cntE; i += 256) {
        uint_t p = staged[gbeg + i];
        int dl = (p >> 16) & 255;
        int lofs = atomicAdd(&ncnt[dl], 1);
        csr[(size_t)gbeg + nrp[dl] + lofs] = (ushort_t)(p & 0xffffu);
    }
}

// Dense h' = dinv[row]*(x@W), OUTPUT PACKED BF16. Block covers 64 rows.
// lane=row; x per-lane from LDS; W wave-uniform -> scalar loads.
template <int K>
__global__ __launch_bounds__(256) void gemm_kernel(const float* __restrict__ x,
                                                   const float* __restrict__ W,
                                                   const float* __restrict__ dinv,
                                                   ushort_t* __restrict__ out, int nrows) {
    constexpr int KP = K + 4;
    constexpr int NC = K / 4;
    constexpr int YP = 68;
    __shared__ float Xs[64 * KP];
    const int tid = threadIdx.x;
    const int lane = tid & 63;
    const int rowBase = blockIdx.x * 64;

    for (int idx = tid; idx < 64 * NC; idx += 256) {
        int row = idx / NC, kc = idx % NC;
        int r = rowBase + row;
        float4 v = (r < nrows) ? *(const float4*)(x + (size_t)r * K + kc * 4)
                               : make_float4(0.f, 0.f, 0.f, 0.f);
        *(float4*)(&Xs[row * KP + kc * 4]) = v;
    }
    __syncthreads();

    const int c0 = __builtin_amdgcn_readfirstlane((tid >> 6) * 16);
    float acc[16];
#pragma unroll
    for (int i = 0; i < 16; ++i) acc[i] = 0.f;
    const float* Xrow = &Xs[lane * KP];

#pragma unroll 4
    for (int k = 0; k < K; k += 4) {
        float4 xv = *(const float4*)(Xrow + k);
        const float* wp = W + (size_t)k * FD + c0;  // uniform
#pragma unroll
        for (int ci = 0; ci < 16; ++ci) {
            acc[ci] = fmaf(xv.x, wp[ci], acc[ci]);
            acc[ci] = fmaf(xv.y, wp[FD + ci], acc[ci]);
            acc[ci] = fmaf(xv.z, wp[2 * FD + ci], acc[ci]);
            acc[ci] = fmaf(xv.w, wp[3 * FD + ci], acc[ci]);
        }
    }

    int r = rowBase + lane;
    float di = (r < nrows) ? dinv[r] : 0.f;
    __syncthreads();
    float* Ys = Xs;
#pragma unroll
    for (int ci = 0; ci < 16; ++ci) Ys[lane * YP + c0 + ci] = acc[ci] * di;
    __syncthreads();

    for (int i = tid; i < 64 * 16; i += 256) {
        int row = i >> 4, seg = i & 15;
        int rr = rowBase + row;
        if (rr < nrows) {
            float4 v = *(const float4*)(&Ys[row * YP + seg * 4]);
            uint2 p;
            p.x = pack2bf(v.x, v.y);
            p.y = pack2bf(v.z, v.w);
            *(uint2*)(out + (size_t)rr * FD + seg * 4) = p;
        }
    }
}

__device__ __forceinline__ void bf8_acc(uint4 a, float* acc) {
    acc[0] += __uint_as_float(a.x << 16);
    acc[1] += __uint_as_float(a.x & 0xffff0000u);
    acc[2] += __uint_as_float(a.y << 16);
    acc[3] += __uint_as_float(a.y & 0xffff0000u);
    acc[4] += __uint_as_float(a.z << 16);
    acc[5] += __uint_as_float(a.z & 0xffff0000u);
    acc[6] += __uint_as_float(a.w << 16);
    acc[7] += __uint_as_float(a.w & 0xffff0000u);
}

// Pull aggregation + fused epilogue. 8 nodes/wave: 8 lanes x 8 bf16 features each.
template <bool RELU>
__global__ __launch_bounds__(256) void agg_fused(
    const int* __restrict__ rowptr, const ushort_t* __restrict__ csr,
    const float* __restrict__ dinv, const ushort_t* __restrict__ h,
    const float* __restrict__ b, float* __restrict__ out, int N) {
    int wid = (blockIdx.x * blockDim.x + threadIdx.x) >> 6;
    int lane = threadIdx.x & 63;
    int l8 = lane & 7;
    int node = wid * 8 + (lane >> 3);
    bool valid = node < N;
    int nd = valid ? node : N - 1;
    int beg = rowptr[nd];
    int end = valid ? rowptr[nd + 1] : beg;
    const uint4* __restrict__ h4 = (const uint4*)h;  // row = 8 uint4
    float acc[8];
#pragma unroll
    for (int k = 0; k < 8; ++k) acc[k] = 0.f;
    bf8_acc(h4[(size_t)nd * 8 + l8], acc);  // self-loop
    int j = beg;
    for (; j + 3 < end; j += 4) {
        int s0 = csr[j], s1 = csr[j + 1], s2 = csr[j + 2], s3 = csr[j + 3];
        uint4 a0 = h4[(size_t)s0 * 8 + l8];
        uint4 a1 = h4[(size_t)s1 * 8 + l8];
        uint4 a2 = h4[(size_t)s2 * 8 + l8];
        uint4 a3 = h4[(size_t)s3 * 8 + l8];
        bf8_acc(a0, acc); bf8_acc(a1, acc); bf8_acc(a2, acc); bf8_acc(a3, acc);
    }
    for (; j < end; ++j) bf8_acc(h4[(size_t)csr[j] * 8 + l8], acc);

    float di = dinv[nd];
    float4 b0 = *(const float4*)(b + l8 * 8);
    float4 b1 = *(const float4*)(b + l8 * 8 + 4);
    float4 v0, v1;
    v0.x = fmaf(di, acc[0], b0.x); v0.y = fmaf(di, acc[1], b0.y);
    v0.z = fmaf(di, acc[2], b0.z); v0.w = fmaf(di, acc[3], b0.w);
    v1.x = fmaf(di, acc[4], b1.x); v1.y = fmaf(di, acc[5], b1.y);
    v1.z = fmaf(di, acc[6], b1.z); v1.w = fmaf(di, acc[7], b1.w);
    if (RELU) {
        v0.x = fmaxf(v0.x, 0.f); v0.y = fmaxf(v0.y, 0.f);
        v0.z = fmaxf(v0.z, 0.f); v0.w = fmaxf(v0.w, 0.f);
        v1.x = fmaxf(v1.x, 0.f); v1.y = fmaxf(v1.y, 0.f);
        v1.z = fmaxf(v1.z, 0.f); v1.w = fmaxf(v1.w, 0.f);
    }
    if (valid) {
        float* op = out + (size_t)node * FD + l8 * 8;
        *(float4*)op = v0;
        *(float4*)(op + 4) = v1;
    }
}

extern "C" void kernel_launch(void* const* d_in, const int* in_sizes, int n_in,
                              void* d_out, int out_size, void* d_ws, size_t ws_size,
                              hipStream_t stream) {
    const float* x  = (const float*)d_in[0];
    const int*   ei = (const int*)d_in[1];
    const float* W1 = (const float*)d_in[2];
    const float* b1 = (const float*)d_in[3];
    const float* W2 = (const float*)d_in[4];
    const float* b2 = (const float*)d_in[5];
    const float* W3 = (const float*)d_in[6];
    const float* b3 = (const float*)d_in[7];
    float* out = (float*)d_out;

    const int N = in_sizes[0] / 128;  // 50000
    const int E = in_sizes[1] / 2;    // 800000
    const int* src = ei;
    const int* dst = ei + E;
    const int NB = (N + 255) / 256;   // 196 buckets (<=256 required)

    // workspace layout
    float*    f1     = (float*)d_ws;                     // N*FD f32
    ushort_t* hB     = (ushort_t*)(f1 + (size_t)N * FD); // N*FD bf16
    float*    dinv   = (float*)(hB + (size_t)N * FD);    // N
    int*      rowptr = (int*)(dinv + N);                 // N+1
    int*   bucketCnt    = rowptr + N + 1;                // NB
    int*   bucketBase   = bucketCnt + NB;                // NB+1
    int*   bucketCursor = bucketBase + NB + 1;           // NB
    uint_t*   staged = (uint_t*)(bucketCursor + NB);     // E
    ushort_t* csr    = (ushort_t*)(staged + E);          // E

    const int nEBlk = (E + P1CHUNK - 1) / P1CHUNK;
    dim3 blk(256);
    dim3 gGemm((N + 63) / 64);
    dim3 gAgg((N + 31) / 32);  // 8 nodes/wave, 4 waves/block

    // CSR build: histogram -> scan -> two-pass bin-scatter -> per-bucket sort
    hipMemsetAsync(bucketCnt, 0, (size_t)NB * sizeof(int), stream);
    bucket_count<<<dim3(nEBlk), blk, 0, stream>>>(dst, bucketCnt, E);
    scan_buckets<<<dim3(1), blk, 0, stream>>>(bucketCnt, bucketBase, bucketCursor,
                                              rowptr, NB, N, E);
    bin_scatter<<<dim3(nEBlk), blk, 0, stream>>>(src, dst, bucketCursor, staged, E);
    bucket_sort<<<dim3(NB), blk, 0, stream>>>(staged, bucketBase, rowptr, dinv, csr, N);

    // Layer 1
    gemm_kernel<128><<<gGemm, blk, 0, stream>>>(x, W1, dinv, hB, N);
    agg_fused<true><<<gAgg, blk, 0, stream>>>(rowptr, csr, dinv, hB, b1, f1, N);

    // Layer 2
    gemm_kernel<64><<<gGemm, blk, 0, stream>>>(f1, W2, dinv, hB, N);
    agg_fused<true><<<gAgg, blk, 0, stream>>>(rowptr, csr, dinv, hB, b2, f1, N);

    // Layer 3
    gemm_kernel<64><<<gGemm, blk, 0, stream>>>(f1, W3, dinv, hB, N);
    agg_fused<false><<<gAgg, blk, 0, stream>>>(rowptr, csr, dinv, hB, b3, out, N);
}